// Round 5
// baseline (295.235 us; speedup 1.0000x reference)
//
#include <hip/hip_runtime.h>
#include <cstdint>
#include <cstddef>

// Quantized linear (Brevitas-style int8 per-tensor symmetric).
//   x [N=32768, K=1024] f32, w [M=1024, K=1024] f32, bias [M] f32.
//   sx = max|x|/127, sw = max|w|/127; qx = clip(rne(x/sx)) int8, qw likewise
//   out[n,m] = (sum_k qx[n,k]*qw[m,k]) * sx*sw + bias[m]   (f32)
//
// ws layout:
//   [0..7]      2 floats: final amax_x, amax_w  (written by quant kernel)
//   [64..]      544 float per-block partial maxes (512 for x, 32 for w)
//   [4096..]    qx (N*K int8), then qw (M*K int8)

typedef int v4i __attribute__((ext_vector_type(4)));
typedef int v16i __attribute__((ext_vector_type(16)));

#define QMAXF 127.0f
#define KDIM 1024
#define MDIM 1024
#define NBX 512   // absmax blocks for x
#define NBW 32    // absmax blocks for w

// ---------------- pass 1: per-block partial |max| (no atomics, no init) ----
__global__ __launch_bounds__(256) void absmax_partial(
    const float4* __restrict__ x, int nx4,
    const float4* __restrict__ w, int nw4,
    float* __restrict__ partials) {
  const int b = blockIdx.x;
  const bool isw = (b >= NBX);
  const float4* __restrict__ p = isw ? w : x;
  const int n4 = isw ? nw4 : nx4;
  const int nb = isw ? NBW : NBX;
  const int bb = isw ? (b - NBX) : b;
  const int stride = nb * 256;

  float m0 = 0.f, m1 = 0.f, m2 = 0.f, m3 = 0.f;
  int i = bb * 256 + threadIdx.x;
  for (; i + 3 * stride < n4; i += 4 * stride) {
    float4 v0 = p[i], v1 = p[i + stride], v2 = p[i + 2 * stride],
           v3 = p[i + 3 * stride];
    m0 = fmaxf(m0, fmaxf(fmaxf(fabsf(v0.x), fabsf(v0.y)),
                         fmaxf(fabsf(v0.z), fabsf(v0.w))));
    m1 = fmaxf(m1, fmaxf(fmaxf(fabsf(v1.x), fabsf(v1.y)),
                         fmaxf(fabsf(v1.z), fabsf(v1.w))));
    m2 = fmaxf(m2, fmaxf(fmaxf(fabsf(v2.x), fabsf(v2.y)),
                         fmaxf(fabsf(v2.z), fabsf(v2.w))));
    m3 = fmaxf(m3, fmaxf(fmaxf(fabsf(v3.x), fabsf(v3.y)),
                         fmaxf(fabsf(v3.z), fabsf(v3.w))));
  }
  for (; i < n4; i += stride) {
    float4 v = p[i];
    m0 = fmaxf(m0, fmaxf(fmaxf(fabsf(v.x), fabsf(v.y)),
                         fmaxf(fabsf(v.z), fabsf(v.w))));
  }
  float m = fmaxf(fmaxf(m0, m1), fmaxf(m2, m3));
  for (int off = 32; off; off >>= 1) m = fmaxf(m, __shfl_down(m, off, 64));
  __shared__ float wm[4];
  const int lane = threadIdx.x & 63, wid = threadIdx.x >> 6;
  if (lane == 0) wm[wid] = m;
  __syncthreads();
  if (threadIdx.x == 0)
    partials[b] = fmaxf(fmaxf(wm[0], wm[1]), fmaxf(wm[2], wm[3]));
}

// ---------------- pass 2: reduce partials + quantize (16 elems/iter) -------
__global__ __launch_bounds__(256) void quant2(
    const float4* __restrict__ x, int nx16,
    const float4* __restrict__ w, int nw16,
    const float* __restrict__ partials,
    v4i* __restrict__ qx, v4i* __restrict__ qw,
    float* __restrict__ amax_out) {
  const int sel = blockIdx.y;
  // reduce this tensor's partials (identical result in every block)
  const float* pp = partials + (sel ? NBX : 0);
  const int np = sel ? NBW : NBX;
  float m = 0.f;
  for (int i = threadIdx.x; i < np; i += 256) m = fmaxf(m, pp[i]);
  for (int off = 32; off; off >>= 1) m = fmaxf(m, __shfl_down(m, off, 64));
  __shared__ float wm[4];
  __shared__ float bmax;
  const int lane = threadIdx.x & 63, wid = threadIdx.x >> 6;
  if (lane == 0) wm[wid] = m;
  __syncthreads();
  if (threadIdx.x == 0) {
    float bm = fmaxf(fmaxf(wm[0], wm[1]), fmaxf(wm[2], wm[3]));
    bmax = bm;
    if (blockIdx.x == 0) amax_out[sel] = bm;  // publish for GEMM epilogue
  }
  __syncthreads();
  const float amax = bmax;
  const float r = QMAXF / amax;

  const float4* __restrict__ p = sel ? w : x;
  const int n16 = sel ? nw16 : nx16;
  v4i* __restrict__ q = sel ? qw : qx;

  for (int i = blockIdx.x * 256 + threadIdx.x; i < n16;
       i += gridDim.x * 256) {
    float4 v0 = p[4 * i], v1 = p[4 * i + 1], v2 = p[4 * i + 2],
           v3 = p[4 * i + 3];
    v4i o;
#define QPK(V)                                                         \
  ((((int)fminf(fmaxf(rintf((V).x * r), -QMAXF), QMAXF)) & 255) |      \
   ((((int)fminf(fmaxf(rintf((V).y * r), -QMAXF), QMAXF)) & 255) << 8) | \
   ((((int)fminf(fmaxf(rintf((V).z * r), -QMAXF), QMAXF)) & 255) << 16) | \
   ((((int)fminf(fmaxf(rintf((V).w * r), -QMAXF), QMAXF)) & 255) << 24))
    o[0] = QPK(v0);
    o[1] = QPK(v1);
    o[2] = QPK(v2);
    o[3] = QPK(v3);
#undef QPK
    q[i] = o;
  }
}

// ---------------- pass 3: i8 MFMA GEMM, 256x256 tile, 32x32x32 MFMA -------
// 16x16x64 quadrant-phasing was LDS-read-pipe bound (48 ds_read_b128 per
// K-tile per wave; floor ~31us > MFMA floor 17us).  32x32x32 i8 moves 2x the
// ops per LDS byte; k-slice phasing reads each operand fragment exactly once
// (24 b128 per K-tile per wave):
//   LDS/K-tile/CU ~2304cy  ==  MFMA/K-tile/SIMD ~2343cy  -> MFMA-bound.
//
// Structure per K-tile (BK=128 = 4 k-slices of 32; 2 phases of 2 slices):
//   ph0: 12 ds_read (ks0,1) ; stage FULL tile t+1 (8 gl_lds) ;
//        s_barrier ; 16 MFMA
//   ph1: 12 ds_read (ks2,3) ; vmcnt(0)+lgkmcnt(0) [vm: staged loads issued
//        a full phase (~1100cy) earlier -> covered drain; lgkm RACE FIX:
//        ph1's reads are the LAST readers of this buffer and must complete
//        before any wave passes this barrier and issues next tile's DMA
//        writes into it — in-flight ds_read vs global_load_lds write is
//        otherwise unordered] ; s_barrier ; 16 MFMA
// Dbuf: reads from buf, stage into buf^1 -> write/read always disjoint
// within a phase; cross-swap safety via the ph1 drain above.
//
// Fragment layouts: A/B operand: row = lane&31, k = (lane>>5)*16 + idx
// -> lane's 16B seg s = slice*2 + (lane>>5).  C/D (verified m74/m101,
// dtype-independent): col = lane&31 = m (B-rows), row = (reg&3)+8*(reg>>2)
// +4*(lane>>5) = n (A-rows).

__device__ __forceinline__ void ld_lds16(const void* g, void* l) {
  __builtin_amdgcn_global_load_lds(
      (__attribute__((address_space(1))) void*)(void*)g,
      (__attribute__((address_space(3))) void*)l, 16, 0, 0);
}

#define SBAR() asm volatile("s_barrier" ::: "memory")
#define WAITV(n) asm volatile("s_waitcnt vmcnt(" #n ")" ::: "memory")
#define WAITVLG() asm volatile("s_waitcnt vmcnt(0) lgkmcnt(0)" ::: "memory")

#define BK 128
#define BMT 256
#define BNT 256

__global__ __launch_bounds__(512, 2) void gemm_i8(
    const char* __restrict__ qx, const char* __restrict__ qw,
    const float* __restrict__ bias, const float* __restrict__ amax,
    float* __restrict__ out) {
  __shared__ __align__(16) char smA[2][BNT * BK];
  __shared__ __align__(16) char smB[2][BMT * BK];

  const int tid = threadIdx.x;
  const int wave = tid >> 6;
  const int lane = tid & 63;

  // XCD-bijective block swizzle: 512 blocks, 8 XCDs, 64 blocks per XCD.
  const int p = blockIdx.x;
  const int lb = (p & 7) * 64 + (p >> 3);
  const int bm = lb >> 7;   // 0..3
  const int bn = lb & 127;  // 0..127

  const int wn = wave >> 1;  // 0..3: N quadrant (64 rows)
  const int wm = wave & 1;   // 0..1: M half (128 rows)

  const char* __restrict__ xb = qx + (size_t)bn * BNT * KDIM;
  const char* __restrict__ wb = qw + (size_t)bm * BMT * KDIM;

  const int lrow = lane >> 3;         // row within an 8-row staging slab
  const int sgx = (lane & 7) ^ lrow;  // swizzled source segment
  const int gcol = sgx * 16;
  const int l31 = lane & 31;
  const int lhi = lane >> 5;          // 0/1: k-halfgroup within a slice

  v16i acc[2][4] = {};

  // stage the FULL next tile: 4 B-slabs + 4 A-slabs per wave (8 rows each)
#define STAGE8(bufc, kb) do {                                               \
    _Pragma("unroll") for (int c = 0; c < 4; ++c) {                         \
      const int rb = (wave * 4 + c) * 8;                                    \
      ld_lds16(wb + (size_t)(rb + lrow) * KDIM + (kb) + gcol,               \
               &smB[bufc][rb * BK]);                                        \
    }                                                                       \
    _Pragma("unroll") for (int c = 0; c < 4; ++c) {                         \
      const int rb = (wave * 4 + c) * 8;                                    \
      ld_lds16(xb + (size_t)(rb + lrow) * KDIM + (kb) + gcol,               \
               &smA[bufc][rb * BK]);                                        \
    }                                                                       \
  } while (0)

  // one phase: 12 ds_read_b128 (2 k-slices) ; optional stage ; waits ;
  // ONE barrier ; 16 MFMA under setprio.
#define PHASE(bufc, ph, STG, WT) do {                                       \
    v4i a_[2][2], b_[2][4];                                                 \
    _Pragma("unroll") for (int ks = 0; ks < 2; ++ks) {                      \
      const int s = ((ph) * 2 + ks) * 2 + lhi;  /* 16B seg 0..7 */          \
      _Pragma("unroll") for (int i = 0; i < 2; ++i) {                       \
        const int r = wn * 64 + i * 32 + l31;                               \
        a_[ks][i] = *(const v4i*)(&smA[bufc][r * BK + ((s ^ (r & 7)) * 16)]);\
      }                                                                     \
      _Pragma("unroll") for (int j = 0; j < 4; ++j) {                       \
        const int r = wm * 128 + j * 32 + l31;                              \
        b_[ks][j] = *(const v4i*)(&smB[bufc][r * BK + ((s ^ (r & 7)) * 16)]);\
      }                                                                     \
    }                                                                       \
    STG;                                                                    \
    WT;                                                                     \
    SBAR();                                                                 \
    __builtin_amdgcn_s_setprio(1);                                          \
    _Pragma("unroll") for (int ks = 0; ks < 2; ++ks)                        \
      _Pragma("unroll") for (int i = 0; i < 2; ++i)                         \
        _Pragma("unroll") for (int j = 0; j < 4; ++j)                       \
          acc[i][j] = __builtin_amdgcn_mfma_i32_32x32x32_i8(                \
              a_[ks][i], b_[ks][j], acc[i][j], 0, 0, 0);                    \
    __builtin_amdgcn_s_setprio(0);                                          \
  } while (0)

  // K-tile t in buf (t&1); stage t+1 into buf^1 during ph0.
  // ph1 pre-barrier: vmcnt(0) for staged tile t+1 (covered by one phase),
  // lgkmcnt(0) so ph1's reads of buf complete before buf is re-staged.
#define TILE(bufc, kb1)                                                     \
    PHASE(bufc, 0, STAGE8((bufc) ^ 1, kb1), (void)0);                       \
    PHASE(bufc, 1, (void)0, WAITVLG());

  // prologue: tile 0 into buf 0, full drain (initial fill, unavoidable)
  STAGE8(0, 0);
  WAITV(0);
  SBAR();

  TILE(0, 1 * BK);
  TILE(1, 2 * BK);
  TILE(0, 3 * BK);
  TILE(1, 4 * BK);
  TILE(0, 5 * BK);
  TILE(1, 6 * BK);
  TILE(0, 7 * BK);
  // tail tile 7 in buf 1: nothing to stage, nothing outstanding
  PHASE(1, 0, (void)0, (void)0);
  PHASE(1, 1, (void)0, (void)0);

#undef TILE
#undef PHASE
#undef STAGE8

  // epilogue: 32x32 C/D map: m = bm*256+wm*128+j*32+(lane&31),
  //           n = bn*256+wn*64+i*32 + (r&3)+8*(r>>2)+4*(lane>>5)
  const float sfac = (amax[0] / QMAXF) * (amax[1] / QMAXF);
  const int mcol = bm * BMT + wm * 128 + l31;
  const int nb0 = bn * BNT + wn * 64 + 4 * lhi;
  float bv[4];
#pragma unroll
  for (int j = 0; j < 4; ++j) bv[j] = bias[mcol + j * 32];
#pragma unroll
  for (int i = 0; i < 2; ++i) {
#pragma unroll
    for (int r = 0; r < 16; ++r) {
      const int n = nb0 + i * 32 + (r & 3) + 8 * (r >> 2);
      float* orow = out + (size_t)n * MDIM + mcol;
#pragma unroll
      for (int j = 0; j < 4; ++j)
        orow[j * 32] = (float)acc[i][j][r] * sfac + bv[j];
    }
  }
}

extern "C" void kernel_launch(void* const* d_in, const int* in_sizes, int n_in,
                              void* d_out, int out_size, void* d_ws, size_t ws_size,
                              hipStream_t stream) {
  const float* x = (const float*)d_in[0];
  const float* w = (const float*)d_in[1];
  const float* bias = (const float*)d_in[2];
  float* out = (float*)d_out;

  const int NX = in_sizes[0];  // N*K = 33554432
  const int NW = in_sizes[1];  // M*K = 1048576
  const int N = NX / KDIM;     // 32768

  float* amax = (float*)d_ws;
  float* partials = (float*)((char*)d_ws + 64);
  char* qx = (char*)d_ws + 4096;
  char* qw = qx + (size_t)NX;

  absmax_partial<<<NBX + NBW, 256, 0, stream>>>(
      (const float4*)x, NX / 4, (const float4*)w, NW / 4, partials);

  dim3 qgrid(1024, 2);
  quant2<<<qgrid, 256, 0, stream>>>((const float4*)x, NX / 16,
                                    (const float4*)w, NW / 16, partials,
                                    (v4i*)qx, (v4i*)qw, amax);

  // 512 blocks = (M/256=4) x (N/256=128), XCD-chunked inside the kernel
  gemm_i8<<<dim3(512), 512, 0, stream>>>(qx, qw, bias, amax, out);
}

// Round 6
// 292.101 us; speedup vs baseline: 1.0107x; 1.0107x over previous
//
#include <hip/hip_runtime.h>
#include <cstdint>
#include <cstddef>

// Quantized linear (Brevitas-style int8 per-tensor symmetric).
//   x [N=32768, K=1024] f32, w [M=1024, K=1024] f32, bias [M] f32.
//   sx = max|x|/127, sw = max|w|/127; qx = clip(rne(x/sx)) int8, qw likewise
//   out[n,m] = (sum_k qx[n,k]*qw[m,k]) * sx*sw + bias[m]   (f32)
//
// ws layout:
//   [0..7]      2 floats: final amax_x, amax_w  (written by quant kernel)
//   [64..]      544 float per-block partial maxes (512 for x, 32 for w)
//   [4096..]    qx (N*K int8), then qw (M*K int8)

typedef int v4i __attribute__((ext_vector_type(4)));
typedef int v16i __attribute__((ext_vector_type(16)));

#define QMAXF 127.0f
#define KDIM 1024
#define MDIM 1024
#define NBX 512   // absmax blocks for x
#define NBW 32    // absmax blocks for w

// ---------------- pass 1: per-block partial |max| (no atomics, no init) ----
__global__ __launch_bounds__(256) void absmax_partial(
    const float4* __restrict__ x, int nx4,
    const float4* __restrict__ w, int nw4,
    float* __restrict__ partials) {
  const int b = blockIdx.x;
  const bool isw = (b >= NBX);
  const float4* __restrict__ p = isw ? w : x;
  const int n4 = isw ? nw4 : nx4;
  const int nb = isw ? NBW : NBX;
  const int bb = isw ? (b - NBX) : b;
  const int stride = nb * 256;

  float m0 = 0.f, m1 = 0.f, m2 = 0.f, m3 = 0.f;
  int i = bb * 256 + threadIdx.x;
  for (; i + 3 * stride < n4; i += 4 * stride) {
    float4 v0 = p[i], v1 = p[i + stride], v2 = p[i + 2 * stride],
           v3 = p[i + 3 * stride];
    m0 = fmaxf(m0, fmaxf(fmaxf(fabsf(v0.x), fabsf(v0.y)),
                         fmaxf(fabsf(v0.z), fabsf(v0.w))));
    m1 = fmaxf(m1, fmaxf(fmaxf(fabsf(v1.x), fabsf(v1.y)),
                         fmaxf(fabsf(v1.z), fabsf(v1.w))));
    m2 = fmaxf(m2, fmaxf(fmaxf(fabsf(v2.x), fabsf(v2.y)),
                         fmaxf(fabsf(v2.z), fabsf(v2.w))));
    m3 = fmaxf(m3, fmaxf(fmaxf(fabsf(v3.x), fabsf(v3.y)),
                         fmaxf(fabsf(v3.z), fabsf(v3.w))));
  }
  for (; i < n4; i += stride) {
    float4 v = p[i];
    m0 = fmaxf(m0, fmaxf(fmaxf(fabsf(v.x), fabsf(v.y)),
                         fmaxf(fabsf(v.z), fabsf(v.w))));
  }
  float m = fmaxf(fmaxf(m0, m1), fmaxf(m2, m3));
  for (int off = 32; off; off >>= 1) m = fmaxf(m, __shfl_down(m, off, 64));
  __shared__ float wm[4];
  const int lane = threadIdx.x & 63, wid = threadIdx.x >> 6;
  if (lane == 0) wm[wid] = m;
  __syncthreads();
  if (threadIdx.x == 0)
    partials[b] = fmaxf(fmaxf(wm[0], wm[1]), fmaxf(wm[2], wm[3]));
}

// ---------------- pass 2: reduce partials + quantize (16 elems/iter) -------
__global__ __launch_bounds__(256) void quant2(
    const float4* __restrict__ x, int nx16,
    const float4* __restrict__ w, int nw16,
    const float* __restrict__ partials,
    v4i* __restrict__ qx, v4i* __restrict__ qw,
    float* __restrict__ amax_out) {
  const int sel = blockIdx.y;
  // reduce this tensor's partials (identical result in every block)
  const float* pp = partials + (sel ? NBX : 0);
  const int np = sel ? NBW : NBX;
  float m = 0.f;
  for (int i = threadIdx.x; i < np; i += 256) m = fmaxf(m, pp[i]);
  for (int off = 32; off; off >>= 1) m = fmaxf(m, __shfl_down(m, off, 64));
  __shared__ float wm[4];
  __shared__ float bmax;
  const int lane = threadIdx.x & 63, wid = threadIdx.x >> 6;
  if (lane == 0) wm[wid] = m;
  __syncthreads();
  if (threadIdx.x == 0) {
    float bm = fmaxf(fmaxf(wm[0], wm[1]), fmaxf(wm[2], wm[3]));
    bmax = bm;
    if (blockIdx.x == 0) amax_out[sel] = bm;  // publish for GEMM epilogue
  }
  __syncthreads();
  const float amax = bmax;
  const float r = QMAXF / amax;

  const float4* __restrict__ p = sel ? w : x;
  const int n16 = sel ? nw16 : nx16;
  v4i* __restrict__ q = sel ? qw : qx;

  for (int i = blockIdx.x * 256 + threadIdx.x; i < n16;
       i += gridDim.x * 256) {
    float4 v0 = p[4 * i], v1 = p[4 * i + 1], v2 = p[4 * i + 2],
           v3 = p[4 * i + 3];
    v4i o;
#define QPK(V)                                                         \
  ((((int)fminf(fmaxf(rintf((V).x * r), -QMAXF), QMAXF)) & 255) |      \
   ((((int)fminf(fmaxf(rintf((V).y * r), -QMAXF), QMAXF)) & 255) << 8) | \
   ((((int)fminf(fmaxf(rintf((V).z * r), -QMAXF), QMAXF)) & 255) << 16) | \
   ((((int)fminf(fmaxf(rintf((V).w * r), -QMAXF), QMAXF)) & 255) << 24))
    o[0] = QPK(v0);
    o[1] = QPK(v1);
    o[2] = QPK(v2);
    o[3] = QPK(v3);
#undef QPK
    q[i] = o;
  }
}

// ---------------- pass 3: i8 MFMA GEMM, 256x256 tile, 32x32x32 MFMA -------
// R5 post-mortem: three different K-loop structures all ~80us; MfmaUtil 16%,
// VALU 8%, HBM 30%, conflicts 0 -> stall-bound on OPERAND STREAMING.  A (qx)
// was re-fetched 4x (M/BMT) and the old swizzle put the 4 bm-blocks of each
// bn on 4 DIFFERENT XCDs -> every XCD pulled its own copy of every A panel
// from L3/HBM; per-tile barrier-synced staging bursts (16 MB chip-wide)
// exposed ~1.5-2us of vmcnt stall per K-tile.
//
// R6 fix (mapping only): XCD-local A-panel sharing.  XCD x = p&7 owns
// bn in [x*16, x*16+16); within it, bn-major x bm-minor:
//   i = p>>3;  bn = x*16 + (i>>2);  bm = i&3          (bijective)
// The 32 concurrently-resident blocks per XCD = 8 A-panels (2 MB) x 4
// B-panels (1 MB) = 3 MB <= 4 MB L2.  A is HBM-fetched once (33.5 MB, not
// 134); staging re-reads are L2-hits, covered by one compute phase.
//
// Structure per K-tile (BK=128 = 4 k-slices of 32; 2 phases of 2 slices):
//   ph0: 12 ds_read (ks0,1) ; stage FULL tile t+1 (8 gl_lds) ;
//        s_barrier ; 16 MFMA
//   ph1: 12 ds_read (ks2,3) ; vmcnt(0)+lgkmcnt(0) [vm: staged loads now
//        L2-hit -> covered; lgkm: ph1's reads are the LAST readers of this
//        buffer and must complete before any wave passes the barrier and
//        DMA-writes into it] ; s_barrier ; 16 MFMA
// Dbuf: reads from buf, stage into buf^1.
//
// Fragment layouts: A/B operand: row = lane&31, k = (lane>>5)*16 + idx
// -> lane's 16B seg s = slice*2 + (lane>>5).  C/D (verified m74/m101,
// dtype-independent): col = lane&31 = m (B-rows), row = (reg&3)+8*(reg>>2)
// +4*(lane>>5) = n (A-rows).

__device__ __forceinline__ void ld_lds16(const void* g, void* l) {
  __builtin_amdgcn_global_load_lds(
      (__attribute__((address_space(1))) void*)(void*)g,
      (__attribute__((address_space(3))) void*)l, 16, 0, 0);
}

#define SBAR() asm volatile("s_barrier" ::: "memory")
#define WAITV(n) asm volatile("s_waitcnt vmcnt(" #n ")" ::: "memory")
#define WAITVLG() asm volatile("s_waitcnt vmcnt(0) lgkmcnt(0)" ::: "memory")

#define BK 128
#define BMT 256
#define BNT 256

__global__ __launch_bounds__(512, 2) void gemm_i8(
    const char* __restrict__ qx, const char* __restrict__ qw,
    const float* __restrict__ bias, const float* __restrict__ amax,
    float* __restrict__ out) {
  __shared__ __align__(16) char smA[2][BNT * BK];
  __shared__ __align__(16) char smB[2][BMT * BK];

  const int tid = threadIdx.x;
  const int wave = tid >> 6;
  const int lane = tid & 63;

  // XCD-local A-panel sharing (see header).  p&7 = XCD (round-robin
  // dispatch heuristic); bn-major x bm-minor within the XCD so the 32
  // resident blocks share 8 A-panels + all 4 B-panels in that XCD's L2.
  const int p = blockIdx.x;
  const int i_ = p >> 3;
  const int bn = (p & 7) * 16 + (i_ >> 2);  // 0..127
  const int bm = i_ & 3;                    // 0..3

  const int wn = wave >> 1;  // 0..3: N quadrant (64 rows)
  const int wm = wave & 1;   // 0..1: M half (128 rows)

  const char* __restrict__ xb = qx + (size_t)bn * BNT * KDIM;
  const char* __restrict__ wb = qw + (size_t)bm * BMT * KDIM;

  const int lrow = lane >> 3;         // row within an 8-row staging slab
  const int sgx = (lane & 7) ^ lrow;  // swizzled source segment
  const int gcol = sgx * 16;
  const int l31 = lane & 31;
  const int lhi = lane >> 5;          // 0/1: k-halfgroup within a slice

  v16i acc[2][4] = {};

  // stage the FULL next tile: 4 B-slabs + 4 A-slabs per wave (8 rows each)
#define STAGE8(bufc, kb) do {                                               \
    _Pragma("unroll") for (int c = 0; c < 4; ++c) {                         \
      const int rb = (wave * 4 + c) * 8;                                    \
      ld_lds16(wb + (size_t)(rb + lrow) * KDIM + (kb) + gcol,               \
               &smB[bufc][rb * BK]);                                        \
    }                                                                       \
    _Pragma("unroll") for (int c = 0; c < 4; ++c) {                         \
      const int rb = (wave * 4 + c) * 8;                                    \
      ld_lds16(xb + (size_t)(rb + lrow) * KDIM + (kb) + gcol,               \
               &smA[bufc][rb * BK]);                                        \
    }                                                                       \
  } while (0)

  // one phase: 12 ds_read_b128 (2 k-slices) ; optional stage ; waits ;
  // ONE barrier ; 16 MFMA under setprio.
#define PHASE(bufc, ph, STG, WT) do {                                       \
    v4i a_[2][2], b_[2][4];                                                 \
    _Pragma("unroll") for (int ks = 0; ks < 2; ++ks) {                      \
      const int s = ((ph) * 2 + ks) * 2 + lhi;  /* 16B seg 0..7 */          \
      _Pragma("unroll") for (int i = 0; i < 2; ++i) {                       \
        const int r = wn * 64 + i * 32 + l31;                               \
        a_[ks][i] = *(const v4i*)(&smA[bufc][r * BK + ((s ^ (r & 7)) * 16)]);\
      }                                                                     \
      _Pragma("unroll") for (int j = 0; j < 4; ++j) {                       \
        const int r = wm * 128 + j * 32 + l31;                              \
        b_[ks][j] = *(const v4i*)(&smB[bufc][r * BK + ((s ^ (r & 7)) * 16)]);\
      }                                                                     \
    }                                                                       \
    STG;                                                                    \
    WT;                                                                     \
    SBAR();                                                                 \
    __builtin_amdgcn_s_setprio(1);                                          \
    _Pragma("unroll") for (int ks = 0; ks < 2; ++ks)                        \
      _Pragma("unroll") for (int i = 0; i < 2; ++i)                         \
        _Pragma("unroll") for (int j = 0; j < 4; ++j)                       \
          acc[i][j] = __builtin_amdgcn_mfma_i32_32x32x32_i8(                \
              a_[ks][i], b_[ks][j], acc[i][j], 0, 0, 0);                    \
    __builtin_amdgcn_s_setprio(0);                                          \
  } while (0)

  // K-tile t in buf (t&1); stage t+1 into buf^1 during ph0.
#define TILE(bufc, kb1)                                                     \
    PHASE(bufc, 0, STAGE8((bufc) ^ 1, kb1), (void)0);                       \
    PHASE(bufc, 1, (void)0, WAITVLG());

  // prologue: tile 0 into buf 0, full drain (initial fill, unavoidable)
  STAGE8(0, 0);
  WAITV(0);
  SBAR();

  TILE(0, 1 * BK);
  TILE(1, 2 * BK);
  TILE(0, 3 * BK);
  TILE(1, 4 * BK);
  TILE(0, 5 * BK);
  TILE(1, 6 * BK);
  TILE(0, 7 * BK);
  // tail tile 7 in buf 1: nothing to stage, nothing outstanding
  PHASE(1, 0, (void)0, (void)0);
  PHASE(1, 1, (void)0, (void)0);

#undef TILE
#undef PHASE
#undef STAGE8

  // epilogue: 32x32 C/D map: m = bm*256+wm*128+j*32+(lane&31),
  //           n = bn*256+wn*64+i*32 + (r&3)+8*(r>>2)+4*(lane>>5)
  const float sfac = (amax[0] / QMAXF) * (amax[1] / QMAXF);
  const int mcol = bm * BMT + wm * 128 + l31;
  const int nb0 = bn * BNT + wn * 64 + 4 * lhi;
  float bv[4];
#pragma unroll
  for (int j = 0; j < 4; ++j) bv[j] = bias[mcol + j * 32];
#pragma unroll
  for (int i = 0; i < 2; ++i) {
#pragma unroll
    for (int r = 0; r < 16; ++r) {
      const int n = nb0 + i * 32 + (r & 3) + 8 * (r >> 2);
      float* orow = out + (size_t)n * MDIM + mcol;
#pragma unroll
      for (int j = 0; j < 4; ++j)
        orow[j * 32] = (float)acc[i][j][r] * sfac + bv[j];
    }
  }
}

extern "C" void kernel_launch(void* const* d_in, const int* in_sizes, int n_in,
                              void* d_out, int out_size, void* d_ws, size_t ws_size,
                              hipStream_t stream) {
  const float* x = (const float*)d_in[0];
  const float* w = (const float*)d_in[1];
  const float* bias = (const float*)d_in[2];
  float* out = (float*)d_out;

  const int NX = in_sizes[0];  // N*K = 33554432
  const int NW = in_sizes[1];  // M*K = 1048576
  const int N = NX / KDIM;     // 32768

  float* amax = (float*)d_ws;
  float* partials = (float*)((char*)d_ws + 64);
  char* qx = (char*)d_ws + 4096;
  char* qw = qx + (size_t)NX;

  absmax_partial<<<NBX + NBW, 256, 0, stream>>>(
      (const float4*)x, NX / 4, (const float4*)w, NW / 4, partials);

  dim3 qgrid(1024, 2);
  quant2<<<qgrid, 256, 0, stream>>>((const float4*)x, NX / 16,
                                    (const float4*)w, NW / 16, partials,
                                    (v4i*)qx, (v4i*)qw, amax);

  // 512 blocks = (M/256=4) x (N/256=128), XCD-local A-sharing map inside
  gemm_i8<<<dim3(512), 512, 0, stream>>>(qx, qw, bias, amax, out);
}

// Round 7
// 291.720 us; speedup vs baseline: 1.0120x; 1.0013x over previous
//
#include <hip/hip_runtime.h>
#include <cstdint>
#include <cstddef>

// Quantized linear (Brevitas-style int8 per-tensor symmetric).
//   x [N=32768, K=1024] f32, w [M=1024, K=1024] f32, bias [M] f32.
//   sx = max|x|/127, sw = max|w|/127; qx = clip(rne(x/sx)) int8, qw likewise
//   out[n,m] = (sum_k qx[n,k]*qw[m,k]) * sx*sw + bias[m]   (f32)
//
// ws layout:
//   [0..7]      2 floats: final amax_x, amax_w  (written by quant kernel)
//   [64..]      544 float per-block partial maxes (512 for x, 32 for w)
//   [4096..]    qx (N*K int8), then qw (M*K int8)

typedef int v4i __attribute__((ext_vector_type(4)));
typedef int v16i __attribute__((ext_vector_type(16)));

#define QMAXF 127.0f
#define KDIM 1024
#define MDIM 1024
#define NBX 512   // absmax blocks for x
#define NBW 32    // absmax blocks for w

// ---------------- pass 1: per-block partial |max| (no atomics, no init) ----
__global__ __launch_bounds__(256) void absmax_partial(
    const float4* __restrict__ x, int nx4,
    const float4* __restrict__ w, int nw4,
    float* __restrict__ partials) {
  const int b = blockIdx.x;
  const bool isw = (b >= NBX);
  const float4* __restrict__ p = isw ? w : x;
  const int n4 = isw ? nw4 : nx4;
  const int nb = isw ? NBW : NBX;
  const int bb = isw ? (b - NBX) : b;
  const int stride = nb * 256;

  float m0 = 0.f, m1 = 0.f, m2 = 0.f, m3 = 0.f;
  int i = bb * 256 + threadIdx.x;
  for (; i + 3 * stride < n4; i += 4 * stride) {
    float4 v0 = p[i], v1 = p[i + stride], v2 = p[i + 2 * stride],
           v3 = p[i + 3 * stride];
    m0 = fmaxf(m0, fmaxf(fmaxf(fabsf(v0.x), fabsf(v0.y)),
                         fmaxf(fabsf(v0.z), fabsf(v0.w))));
    m1 = fmaxf(m1, fmaxf(fmaxf(fabsf(v1.x), fabsf(v1.y)),
                         fmaxf(fabsf(v1.z), fabsf(v1.w))));
    m2 = fmaxf(m2, fmaxf(fmaxf(fabsf(v2.x), fabsf(v2.y)),
                         fmaxf(fabsf(v2.z), fabsf(v2.w))));
    m3 = fmaxf(m3, fmaxf(fmaxf(fabsf(v3.x), fabsf(v3.y)),
                         fmaxf(fabsf(v3.z), fabsf(v3.w))));
  }
  for (; i < n4; i += stride) {
    float4 v = p[i];
    m0 = fmaxf(m0, fmaxf(fmaxf(fabsf(v.x), fabsf(v.y)),
                         fmaxf(fabsf(v.z), fabsf(v.w))));
  }
  float m = fmaxf(fmaxf(m0, m1), fmaxf(m2, m3));
  for (int off = 32; off; off >>= 1) m = fmaxf(m, __shfl_down(m, off, 64));
  __shared__ float wm[4];
  const int lane = threadIdx.x & 63, wid = threadIdx.x >> 6;
  if (lane == 0) wm[wid] = m;
  __syncthreads();
  if (threadIdx.x == 0)
    partials[b] = fmaxf(fmaxf(wm[0], wm[1]), fmaxf(wm[2], wm[3]));
}

// ---------------- pass 2: reduce partials + quantize (16 elems/iter) -------
__global__ __launch_bounds__(256) void quant2(
    const float4* __restrict__ x, int nx16,
    const float4* __restrict__ w, int nw16,
    const float* __restrict__ partials,
    v4i* __restrict__ qx, v4i* __restrict__ qw,
    float* __restrict__ amax_out) {
  const int sel = blockIdx.y;
  // reduce this tensor's partials (identical result in every block)
  const float* pp = partials + (sel ? NBX : 0);
  const int np = sel ? NBW : NBX;
  float m = 0.f;
  for (int i = threadIdx.x; i < np; i += 256) m = fmaxf(m, pp[i]);
  for (int off = 32; off; off >>= 1) m = fmaxf(m, __shfl_down(m, off, 64));
  __shared__ float wm[4];
  __shared__ float bmax;
  const int lane = threadIdx.x & 63, wid = threadIdx.x >> 6;
  if (lane == 0) wm[wid] = m;
  __syncthreads();
  if (threadIdx.x == 0) {
    float bm = fmaxf(fmaxf(wm[0], wm[1]), fmaxf(wm[2], wm[3]));
    bmax = bm;
    if (blockIdx.x == 0) amax_out[sel] = bm;  // publish for GEMM epilogue
  }
  __syncthreads();
  const float amax = bmax;
  const float r = QMAXF / amax;

  const float4* __restrict__ p = sel ? w : x;
  const int n16 = sel ? nw16 : nx16;
  v4i* __restrict__ q = sel ? qw : qx;

  for (int i = blockIdx.x * 256 + threadIdx.x; i < n16;
       i += gridDim.x * 256) {
    float4 v0 = p[4 * i], v1 = p[4 * i + 1], v2 = p[4 * i + 2],
           v3 = p[4 * i + 3];
    v4i o;
#define QPK(V)                                                         \
  ((((int)fminf(fmaxf(rintf((V).x * r), -QMAXF), QMAXF)) & 255) |      \
   ((((int)fminf(fmaxf(rintf((V).y * r), -QMAXF), QMAXF)) & 255) << 8) | \
   ((((int)fminf(fmaxf(rintf((V).z * r), -QMAXF), QMAXF)) & 255) << 16) | \
   ((((int)fminf(fmaxf(rintf((V).w * r), -QMAXF), QMAXF)) & 255) << 24))
    o[0] = QPK(v0);
    o[1] = QPK(v1);
    o[2] = QPK(v2);
    o[3] = QPK(v3);
#undef QPK
    q[i] = o;
  }
}

// ---------------- pass 3: i8 MFMA GEMM, 128x256 tile, 2 blocks/CU ---------
// R6 post-mortem: five K-loop structures all ~78us.  Shared constant: ONE
// barrier-locked block per CU (128 KiB LDS) -> every stall fully exposed,
// worst being the per-block epilogue (256 KB -> HBM = 10.4us serialized
// per block, x2 rounds = 21us naked) plus per-phase staging drains.
//
// R7: co-residency.  2 blocks/CU requires 16 waves/CU -> <=128 VGPR/wave
// -> per-wave acc <= 64 -> tile 128N x 256M, 8 waves (2 wn x 4 wm), each
// wave a 64x64 output (acc 2x2x16 = 64 VGPR).  BK=64, TRIPLE-buffered LDS:
// 3 x (A 8KB + B 16KB) = 72 KB -> exactly 2 blocks/CU.  One block's
// epilogue/drains/prologue hide under the other's K-loop.
//
// Pipeline (16 K-tiles of BK=64, one phase each):
//   phase t: 8 ds_read_b128 (2 k-slices) from buf[t%3] ;
//            stage tile t+2 into buf[(t+2)%3] (3 gl_lds/wave) ;
//            s_waitcnt vmcnt(3) [tile t+1, staged a FULL phase ago ->
//            covered] lgkmcnt(0) [reads of buf[t%3] must drain: that buf
//            is re-staged by the NEXT phase right after this barrier] ;
//            s_barrier ; 8 MFMA (setprio-wrapped).
//
// Bank swizzle for BK=64 rows (4 x 16B segs): seg' = seg ^ ((row>>1)&3).
// 8 consecutive rows then map to 8 distinct 4-bank groups (16*(r&1) +
// 4*(seg^((r>>1)&3)) covers all 32 banks) -> <=2-way on ds_read_b128
// (free per m136).  Applied on the global SOURCE during gl_lds (dest
// must stay linear) and on the LDS read address.
//
// Fragment layouts (same as R5, verified): A/B operand row = lane&31,
// k-seg s = ks*2 + (lane>>5).  C/D: col = lane&31 = m (B/w rows),
// row = (reg&3)+8*(reg>>2)+4*(lane>>5) = n (A/x rows).

__device__ __forceinline__ void ld_lds16(const void* g, void* l) {
  __builtin_amdgcn_global_load_lds(
      (__attribute__((address_space(1))) void*)(void*)g,
      (__attribute__((address_space(3))) void*)l, 16, 0, 0);
}

#define SBAR() asm volatile("s_barrier" ::: "memory")
#define WAITV(n) asm volatile("s_waitcnt vmcnt(" #n ")" ::: "memory")
#define WAIT_V3_LG() asm volatile("s_waitcnt vmcnt(3) lgkmcnt(0)" ::: "memory")
#define WAIT_V0_LG() asm volatile("s_waitcnt vmcnt(0) lgkmcnt(0)" ::: "memory")

#define BK 64
#define BNT 128   // N rows per block (x)
#define BMT 256   // M rows per block (w)

__global__ __launch_bounds__(512, 4) void gemm_i8(
    const char* __restrict__ qx, const char* __restrict__ qw,
    const float* __restrict__ bias, const float* __restrict__ amax,
    float* __restrict__ out) {
  __shared__ __align__(16) char smA[3][BNT * BK];   // 3 x 8 KB
  __shared__ __align__(16) char smB[3][BMT * BK];   // 3 x 16 KB

  const int tid = threadIdx.x;
  const int wave = tid >> 6;
  const int lane = tid & 63;

  // XCD-local A-panel sharing: XCD x = p&7; 64 concurrent blocks per XCD
  // (2/CU x 32 CU) = 16 bn-panels (16 x 128 KB A) x 4 bm (4 x 256 KB B)
  // = 3 MB <= 4 MB L2.  bn = x*32 + (i>>2), bm = i&3  (bijective).
  const int p = blockIdx.x;
  const int i_ = p >> 3;
  const int bn = (p & 7) * 32 + (i_ >> 2);  // 0..255
  const int bm = i_ & 3;                    // 0..3

  const int wn = wave >> 2;  // 0..1: N 64-row half
  const int wm = wave & 3;   // 0..3: M 64-row quarter

  const char* __restrict__ xb = qx + (size_t)bn * BNT * KDIM;
  const char* __restrict__ wb = qw + (size_t)bm * BMT * KDIM;

  const int lrow = lane >> 2;                            // staging row 0..15
  const int gseg = ((lane & 3) ^ ((lane >> 3) & 3)) * 16;  // swizzled src seg
  const int l31 = lane & 31;
  const int lhi = lane >> 5;

  v16i acc[2][2] = {};

  // stage one K-tile: A 1 chunk/wave (16 rows), B 2 chunks/wave (32 rows)
#define STAGE3(bufc, kb) do {                                               \
    const int ra = wave * 16;                                               \
    ld_lds16(xb + (size_t)(ra + lrow) * KDIM + (kb) + gseg,                 \
             &smA[bufc][ra * BK]);                                          \
    const int rb0 = wave * 32;                                              \
    ld_lds16(wb + (size_t)(rb0 + lrow) * KDIM + (kb) + gseg,                \
             &smB[bufc][rb0 * BK]);                                         \
    ld_lds16(wb + (size_t)(rb0 + 16 + lrow) * KDIM + (kb) + gseg,           \
             &smB[bufc][(rb0 + 16) * BK]);                                  \
  } while (0)

  // one phase: 8 ds_read_b128 ; optional stage ; waits ; barrier ; 8 MFMA
#define PHASE(bufc, STG, WT, BARX) do {                                     \
    v4i a_[2][2], b_[2][2];                                                 \
    _Pragma("unroll") for (int ks = 0; ks < 2; ++ks) {                      \
      const int s = ks * 2 + lhi;  /* 16B seg 0..3 */                       \
      _Pragma("unroll") for (int i = 0; i < 2; ++i) {                       \
        const int r = wn * 64 + i * 32 + l31;                               \
        a_[ks][i] = *(const v4i*)(                                          \
            &smA[bufc][r * BK + ((s ^ ((r >> 1) & 3)) * 16)]);              \
      }                                                                     \
      _Pragma("unroll") for (int j = 0; j < 2; ++j) {                       \
        const int r = wm * 64 + j * 32 + l31;                               \
        b_[ks][j] = *(const v4i*)(                                          \
            &smB[bufc][r * BK + ((s ^ ((r >> 1) & 3)) * 16)]);              \
      }                                                                     \
    }                                                                       \
    STG;                                                                    \
    WT;                                                                     \
    BARX;                                                                   \
    __builtin_amdgcn_s_setprio(1);                                          \
    _Pragma("unroll") for (int ks = 0; ks < 2; ++ks)                        \
      _Pragma("unroll") for (int i = 0; i < 2; ++i)                         \
        _Pragma("unroll") for (int j = 0; j < 2; ++j)                       \
          acc[i][j] = __builtin_amdgcn_mfma_i32_32x32x32_i8(                \
              a_[ks][i], b_[ks][j], acc[i][j], 0, 0, 0);                    \
    __builtin_amdgcn_s_setprio(0);                                          \
  } while (0)

  // prologue: stage tiles 0,1; wait tile0 (3 newest stay in flight); barrier
  STAGE3(0, 0);
  STAGE3(1, BK);
  WAITV(3);
  SBAR();

  // 16 phases; buf = t%3, stage target = (t+2)%3, stage kb = (t+2)*BK
  PHASE(0, STAGE3(2, 2 * BK), WAIT_V3_LG(), SBAR());   // t0
  PHASE(1, STAGE3(0, 3 * BK), WAIT_V3_LG(), SBAR());   // t1
  PHASE(2, STAGE3(1, 4 * BK), WAIT_V3_LG(), SBAR());   // t2
  PHASE(0, STAGE3(2, 5 * BK), WAIT_V3_LG(), SBAR());   // t3
  PHASE(1, STAGE3(0, 6 * BK), WAIT_V3_LG(), SBAR());   // t4
  PHASE(2, STAGE3(1, 7 * BK), WAIT_V3_LG(), SBAR());   // t5
  PHASE(0, STAGE3(2, 8 * BK), WAIT_V3_LG(), SBAR());   // t6
  PHASE(1, STAGE3(0, 9 * BK), WAIT_V3_LG(), SBAR());   // t7
  PHASE(2, STAGE3(1, 10 * BK), WAIT_V3_LG(), SBAR());  // t8
  PHASE(0, STAGE3(2, 11 * BK), WAIT_V3_LG(), SBAR());  // t9
  PHASE(1, STAGE3(0, 12 * BK), WAIT_V3_LG(), SBAR());  // t10
  PHASE(2, STAGE3(1, 13 * BK), WAIT_V3_LG(), SBAR());  // t11
  PHASE(0, STAGE3(2, 14 * BK), WAIT_V3_LG(), SBAR());  // t12
  PHASE(1, STAGE3(0, 15 * BK), WAIT_V3_LG(), SBAR());  // t13
  PHASE(2, (void)0, WAIT_V0_LG(), SBAR());             // t14 (drain t15)
  PHASE(0, (void)0, (void)0, (void)0);                 // t15 (no more staging)

#undef PHASE
#undef STAGE3

  // epilogue: m = bm*256 + wm*64 + j*32 + (lane&31)  (B/w rows = col)
  //           n = bn*128 + wn*64 + i*32 + (r&3)+8*(r>>2)+4*(lane>>5)
  const float sfac = (amax[0] / QMAXF) * (amax[1] / QMAXF);
  const int mbase = bm * BMT + wm * 64 + l31;
  const int nb0 = bn * BNT + wn * 64 + 4 * lhi;
  float bv[2];
#pragma unroll
  for (int j = 0; j < 2; ++j) bv[j] = bias[mbase + j * 32];
#pragma unroll
  for (int i = 0; i < 2; ++i) {
#pragma unroll
    for (int r = 0; r < 16; ++r) {
      const int n = nb0 + i * 32 + (r & 3) + 8 * (r >> 2);
      float* orow = out + (size_t)n * MDIM + mbase;
#pragma unroll
      for (int j = 0; j < 2; ++j)
        orow[j * 32] = (float)acc[i][j][r] * sfac + bv[j];
    }
  }
}

extern "C" void kernel_launch(void* const* d_in, const int* in_sizes, int n_in,
                              void* d_out, int out_size, void* d_ws, size_t ws_size,
                              hipStream_t stream) {
  const float* x = (const float*)d_in[0];
  const float* w = (const float*)d_in[1];
  const float* bias = (const float*)d_in[2];
  float* out = (float*)d_out;

  const int NX = in_sizes[0];  // N*K = 33554432
  const int NW = in_sizes[1];  // M*K = 1048576
  const int N = NX / KDIM;     // 32768

  float* amax = (float*)d_ws;
  float* partials = (float*)((char*)d_ws + 64);
  char* qx = (char*)d_ws + 4096;
  char* qw = qx + (size_t)NX;

  absmax_partial<<<NBX + NBW, 256, 0, stream>>>(
      (const float4*)x, NX / 4, (const float4*)w, NW / 4, partials);

  dim3 qgrid(1024, 2);
  quant2<<<qgrid, 256, 0, stream>>>((const float4*)x, NX / 16,
                                    (const float4*)w, NW / 16, partials,
                                    (v4i*)qx, (v4i*)qw, amax);

  // 1024 blocks = (M/256=4) x (N/128=256), XCD-local map, 2 blocks/CU
  gemm_i8<<<dim3(1024), 512, 0, stream>>>(qx, qw, bias, amax, out);
}